// Round 10
// baseline (114.336 us; speedup 1.0000x reference)
//
#include <hip/hip_runtime.h>
#include <hip/hip_bf16.h>

#define NN 4096      // N = 2*B
#define BB 2048      // B
#define DD 512       // D
#define TM 128       // C tile (M and N)
#define BK 128       // K tile (R5-best: 4 K-iters, 4 barrier drains)
#define NTILE (NN/TM)                 // 32
#define NPAIR (NTILE*(NTILE+1)/2)     // 528 blocks: bi <= bj

typedef __bf16 bf16x8 __attribute__((ext_vector_type(8)));
typedef float  f32x4  __attribute__((ext_vector_type(4)));

// async global->LDS, 16B per lane. LDS dest must be wave-uniform base + lane*16.
#define GLOAD_LDS16(gsrc, ldst)                                                  \
    __builtin_amdgcn_global_load_lds(                                            \
        (__attribute__((address_space(1))) void*)(gsrc),                         \
        (__attribute__((address_space(3))) void*)(ldst), 16, 0, 0)

__device__ __forceinline__ unsigned short f2bf(float x) {
    unsigned int u = __float_as_uint(x);
    unsigned int r = (u + 0x7fffu + ((u >> 16) & 1u)) >> 16;  // RNE; inputs finite
    return (unsigned short)r;
}

// ---------------------------------------------------------------------------
// Kernel A: row-normalize z = [z_i; z_j] -> bf16 zn[N][D]; zero-inits
// rowsum[] and the completion counter (stream order).
// ---------------------------------------------------------------------------
__global__ __launch_bounds__(256) void normalize_kernel(
        const float* __restrict__ z_i, const float* __restrict__ z_j,
        unsigned short* __restrict__ zn, float* __restrict__ rowsum,
        int* __restrict__ cnt) {
    if (threadIdx.x < 4) rowsum[blockIdx.x * 4 + threadIdx.x] = 0.f;
    if (blockIdx.x == 0 && threadIdx.x == 0) *cnt = 0;

    int row  = blockIdx.x * 4 + (threadIdx.x >> 6);
    int lane = threadIdx.x & 63;
    const float* src = (row < BB) ? (z_i + (size_t)row * DD)
                                  : (z_j + (size_t)(row - BB) * DD);
    const float4* s4 = (const float4*)src;
    float4 v0 = s4[lane * 2 + 0];
    float4 v1 = s4[lane * 2 + 1];
    float ss = v0.x*v0.x + v0.y*v0.y + v0.z*v0.z + v0.w*v0.w
             + v1.x*v1.x + v1.y*v1.y + v1.z*v1.z + v1.w*v1.w;
    #pragma unroll
    for (int off = 1; off < 64; off <<= 1) ss += __shfl_xor(ss, off, 64);
    float inv = 1.0f / fmaxf(sqrtf(ss), 1e-8f);

    float f[8] = {v0.x, v0.y, v0.z, v0.w, v1.x, v1.y, v1.z, v1.w};
    unsigned int p[4];
    #pragma unroll
    for (int k = 0; k < 4; ++k) {
        unsigned int lo = f2bf(f[2*k] * inv);
        unsigned int hi = f2bf(f[2*k+1] * inv);
        p[k] = lo | (hi << 16);
    }
    uint4 outv = make_uint4(p[0], p[1], p[2], p[3]);
    *(uint4*)(zn + (size_t)row * DD + lane * 8) = outv;
}

// ---------------------------------------------------------------------------
// Kernel B (R10): R5's exact hot loop (128x128 tiles, BK=128 single-buffered,
// 2 barriers/K-iter, XOR ^(r&15) swizzle, atomic rowsum epilogue, selfsim/
// possim extraction) + FUSED FINAL REDUCE: each block __threadfence()s and
// bumps a completion counter; the last block re-reads rowsum/selfsim/possim
// with agent-scope atomic loads (cross-XCD visibility, G16), computes
// loss_r = log(rowsum_r - exp(selfsim_r)) - possim_r, block-reduces in LDS,
// and writes out[0] = sum/N. Removes the rowfinal launch + its graph gap.
// ---------------------------------------------------------------------------
__global__ __launch_bounds__(256) void simexp_kernel(
        const unsigned short* __restrict__ zn, float* __restrict__ rowsum,
        float* __restrict__ selfsim, float* __restrict__ possim,
        int* __restrict__ cnt, float* __restrict__ out) {
    __shared__ __align__(16) unsigned short As[TM * BK];   // 32 KB
    __shared__ __align__(16) unsigned short Bs[TM * BK];   // 32 KB
    __shared__ bool last_flag;

    // triangular decode: p -> (bi <= bj)
    int p  = blockIdx.x;
    int bj = (int)((sqrtf(8.0f * (float)p + 1.0f) - 1.0f) * 0.5f);
    while ((bj + 1) * (bj + 2) / 2 <= p) ++bj;
    while (bj * (bj + 1) / 2 > p) --bj;
    int bi = p - bj * (bj + 1) / 2;
    const bool diag = (bi == bj);

    const int tid  = threadIdx.x;
    const int wave = tid >> 6, lane = tid & 63;
    const int wr = wave >> 1, wc = wave & 1;   // 2x2 wave grid, 64x64 each
    const int lrow = lane & 15, quad = lane >> 4;

    f32x4 acc[4][4];
    #pragma unroll
    for (int i = 0; i < 4; ++i)
        #pragma unroll
        for (int j = 0; j < 4; ++j) acc[i][j] = (f32x4){0.f, 0.f, 0.f, 0.f};

    const unsigned short* Bsrc = diag ? As : Bs;   // diag tiles reuse As

    for (int kb = 0; kb < DD; kb += BK) {
        __syncthreads();   // protect LDS from previous iter's readers
        #pragma unroll
        for (int it = 0; it < 8; ++it) {
            int t  = it * 256 + tid;       // chunk-slot 0..2047
            int r  = t >> 4;               // tile row 0..127
            int cc = t & 15;               // LDS chunk slot (16 per row)
            int sc = cc ^ (r & 15);        // global source chunk (swizzle)
            GLOAD_LDS16(zn + (size_t)(bi * TM + r) * DD + kb + sc * 8, As + t * 8);
            if (!diag)
                GLOAD_LDS16(zn + (size_t)(bj * TM + r) * DD + kb + sc * 8, Bs + t * 8);
        }
        __syncthreads();   // drains vmcnt(0) before LDS reads

        #pragma unroll
        for (int s = 0; s < 4; ++s) {      // four K=32 steps per BK=128
            bf16x8 a[4], b[4];
            #pragma unroll
            for (int ti = 0; ti < 4; ++ti) {
                int m = wr * 64 + ti * 16 + lrow;
                int q = (s * 4 + quad) ^ (m & 15);
                a[ti] = *(const bf16x8*)&As[m * BK + q * 8];
            }
            #pragma unroll
            for (int tj = 0; tj < 4; ++tj) {
                int n = wc * 64 + tj * 16 + lrow;
                int q = (s * 4 + quad) ^ (n & 15);
                b[tj] = *(const bf16x8*)&Bsrc[n * BK + q * 8];
            }
            #pragma unroll
            for (int ti = 0; ti < 4; ++ti)
                #pragma unroll
                for (int tj = 0; tj < 4; ++tj)
                    acc[ti][tj] = __builtin_amdgcn_mfma_f32_16x16x32_bf16(
                        a[ti], b[tj], acc[ti][tj], 0, 0, 0);
        }
    }

    // Epilogue. C/D layout (verified, absmax 0.0):
    //   tile row = wr*64 + ti*16 + quad*4 + reg, tile col = wc*64 + tj*16 + lrow
    float rowpart[4][4];   // [ti][reg]
    float colpart[4];      // [tj]
    #pragma unroll
    for (int i = 0; i < 4; ++i) {
        colpart[i] = 0.f;
        #pragma unroll
        for (int r = 0; r < 4; ++r) rowpart[i][r] = 0.f;
    }
    #pragma unroll
    for (int ti = 0; ti < 4; ++ti)
        #pragma unroll
        for (int tj = 0; tj < 4; ++tj)
            #pragma unroll
            for (int reg = 0; reg < 4; ++reg) {
                float e = __expf(acc[ti][tj][reg] * 2.0f);
                rowpart[ti][reg] += e;
                colpart[tj]      += e;
            }

    // row-sums: reduce over lrow (16-lane groups)
    #pragma unroll
    for (int ti = 0; ti < 4; ++ti) {
        #pragma unroll
        for (int reg = 0; reg < 4; ++reg) {
            float v = rowpart[ti][reg];
            v += __shfl_xor(v, 1, 64);
            v += __shfl_xor(v, 2, 64);
            v += __shfl_xor(v, 4, 64);
            v += __shfl_xor(v, 8, 64);
            if (lrow == 0)
                atomicAdd(&rowsum[bi * TM + wr * 64 + ti * 16 + quad * 4 + reg], v);
        }
    }
    // col-sums -> rows of bj tile (transpose); skip on diagonal tiles
    if (!diag) {
        #pragma unroll
        for (int tj = 0; tj < 4; ++tj) {
            float v = colpart[tj];
            v += __shfl_xor(v, 16, 64);
            v += __shfl_xor(v, 32, 64);
            if (quad == 0)
                atomicAdd(&rowsum[bj * TM + wc * 64 + tj * 16 + lrow], v);
        }
    }

    // tile-diagonal extraction: lanes lrow>>2==quad in waves wr==wc hold
    // element (r, r) of the tile at acc[ti][ti][lrow&3], r = wr*64+ti*16+lrow.
    const bool posb = (bj == bi + NTILE / 2);   // bj == bi + 16  (col offset B)
    if ((diag || posb) && wr == wc && (lrow >> 2) == quad) {
        #pragma unroll
        for (int ti = 0; ti < 4; ++ti) {
            float v = 2.0f * acc[ti][ti][lrow & 3];
            int R = bi * TM + wr * 64 + ti * 16 + lrow;
            if (diag) {
                selfsim[R] = v;
            } else {
                possim[R]      = v;   // sim[r][r+B]
                possim[R + BB] = v;   // == sim[r+B][r]
            }
        }
    }

    // ---- fused final reduce (last block only) ----
    __threadfence();                       // publish this block's writes
    __syncthreads();                       // all threads' fences done
    if (tid == 0) {
        int old = atomicAdd(cnt, 1);
        last_flag = (old == NPAIR - 1);
    }
    __syncthreads();
    if (!last_flag) return;

    // all 527 other blocks have fenced + counted: their rowsum atomics and
    // selfsim/possim stores are visible via agent-scope loads.
    float sum = 0.f;
    #pragma unroll
    for (int i = 0; i < NN / 256; ++i) {   // 16 coalesced rows per thread
        int r = i * 256 + tid;
        float rs = __hip_atomic_load(&rowsum[r],  __ATOMIC_RELAXED, __HIP_MEMORY_SCOPE_AGENT);
        float ss = __hip_atomic_load(&selfsim[r], __ATOMIC_RELAXED, __HIP_MEMORY_SCOPE_AGENT);
        float ps = __hip_atomic_load(&possim[r],  __ATOMIC_RELAXED, __HIP_MEMORY_SCOPE_AGENT);
        sum += logf(rs - __expf(ss)) - ps;
    }
    float* red = (float*)As;               // reuse LDS for block reduce
    #pragma unroll
    for (int off = 1; off < 64; off <<= 1) sum += __shfl_xor(sum, off, 64);
    if (lane == 0) red[wave] = sum;
    __syncthreads();
    if (tid == 0)
        out[0] = (red[0] + red[1] + red[2] + red[3]) * (1.0f / (float)NN);
}

extern "C" void kernel_launch(void* const* d_in, const int* in_sizes, int n_in,
                              void* d_out, int out_size, void* d_ws, size_t ws_size,
                              hipStream_t stream) {
    const float* z_i = (const float*)d_in[0];
    const float* z_j = (const float*)d_in[1];
    float* out = (float*)d_out;

    unsigned short* zn = (unsigned short*)d_ws;                    // N*D bf16 = 4 MB
    float* rowsum  = (float*)((char*)d_ws + (size_t)NN * DD * 2);  // N floats
    float* selfsim = rowsum + NN;                                  // N floats
    float* possim  = selfsim + NN;                                 // N floats
    int*   cnt     = (int*)(possim + NN);                          // 1 int

    normalize_kernel<<<NN / 4, 256, 0, stream>>>(z_i, z_j, zn, rowsum, cnt);
    simexp_kernel<<<NPAIR, 256, 0, stream>>>(zn, rowsum, selfsim, possim, cnt, out);
}

// Round 11
// 85.253 us; speedup vs baseline: 1.3411x; 1.3411x over previous
//
#include <hip/hip_runtime.h>
#include <hip/hip_bf16.h>

#define NN 4096      // N = 2*B
#define BB 2048      // B
#define DD 512       // D
#define TM 128       // C tile (M and N)
#define BK 128       // K tile (R5-best: 4 K-iters, 4 barrier drains)
#define NTILE (NN/TM)                 // 32
#define NPAIR (NTILE*(NTILE+1)/2)     // 528 blocks: bi <= bj
#define NXCD 8                        // 528 % 8 == 0 -> simple swizzle bijective

typedef __bf16 bf16x8 __attribute__((ext_vector_type(8)));
typedef float  f32x4  __attribute__((ext_vector_type(4)));

// async global->LDS, 16B per lane. LDS dest must be wave-uniform base + lane*16.
#define GLOAD_LDS16(gsrc, ldst)                                                  \
    __builtin_amdgcn_global_load_lds(                                            \
        (__attribute__((address_space(1))) void*)(gsrc),                         \
        (__attribute__((address_space(3))) void*)(ldst), 16, 0, 0)

__device__ __forceinline__ unsigned short f2bf(float x) {
    unsigned int u = __float_as_uint(x);
    unsigned int r = (u + 0x7fffu + ((u >> 16) & 1u)) >> 16;  // RNE; inputs finite
    return (unsigned short)r;
}

// ---------------------------------------------------------------------------
// Kernel A: row-normalize z = [z_i; z_j] -> bf16 zn[N][D]; also zero-inits
// rowsum[] and out[0] (stream order makes these visible to later kernels).
// ---------------------------------------------------------------------------
__global__ __launch_bounds__(256) void normalize_kernel(
        const float* __restrict__ z_i, const float* __restrict__ z_j,
        unsigned short* __restrict__ zn, float* __restrict__ rowsum,
        float* __restrict__ out) {
    if (threadIdx.x < 4) rowsum[blockIdx.x * 4 + threadIdx.x] = 0.f;
    if (blockIdx.x == 0 && threadIdx.x == 0) out[0] = 0.f;

    int row  = blockIdx.x * 4 + (threadIdx.x >> 6);
    int lane = threadIdx.x & 63;
    const float* src = (row < BB) ? (z_i + (size_t)row * DD)
                                  : (z_j + (size_t)(row - BB) * DD);
    const float4* s4 = (const float4*)src;
    float4 v0 = s4[lane * 2 + 0];
    float4 v1 = s4[lane * 2 + 1];
    float ss = v0.x*v0.x + v0.y*v0.y + v0.z*v0.z + v0.w*v0.w
             + v1.x*v1.x + v1.y*v1.y + v1.z*v1.z + v1.w*v1.w;
    #pragma unroll
    for (int off = 1; off < 64; off <<= 1) ss += __shfl_xor(ss, off, 64);
    float inv = 1.0f / fmaxf(sqrtf(ss), 1e-8f);

    float f[8] = {v0.x, v0.y, v0.z, v0.w, v1.x, v1.y, v1.z, v1.w};
    unsigned int p[4];
    #pragma unroll
    for (int k = 0; k < 4; ++k) {
        unsigned int lo = f2bf(f[2*k] * inv);
        unsigned int hi = f2bf(f[2*k+1] * inv);
        p[k] = lo | (hi << 16);
    }
    uint4 outv = make_uint4(p[0], p[1], p[2], p[3]);
    *(uint4*)(zn + (size_t)row * DD + lane * 8) = outv;
}

// ---------------------------------------------------------------------------
// Kernel B: R5's exact hot loop (85.3 us best): 128x128 upper-tri tiles,
// BK=128 single-buffered, 2 barriers/K-iter, XOR ^(r&15) source swizzle,
// atomic rowsum epilogue (R1-R4 A/B), selfsim/possim extraction.
// R11 adds ONLY the T1 XCD-aware chunked swizzle of the tile index:
// consecutive p share the same bj B-panel; chunking 66 consecutive p per
// XCD keeps that panel in one XCD's L2 (R10 profile: FETCH 16.5 MB ~ 4x zn
// -> cross-XCD HBM re-fetch, 900-cyc staging misses). 528 = 8*66 exactly,
// so (p%8)*66 + p/8 is bijective.
// NO fused reduce: R10 showed per-block __threadfence (agent-scope, L2
// writeback on multi-XCD) costs ~25 us. rowfinal stays a separate kernel.
// ---------------------------------------------------------------------------
__global__ __launch_bounds__(256) void simexp_kernel(
        const unsigned short* __restrict__ zn, float* __restrict__ rowsum,
        float* __restrict__ selfsim, float* __restrict__ possim) {
    __shared__ __align__(16) unsigned short As[TM * BK];   // 32 KB
    __shared__ __align__(16) unsigned short Bs[TM * BK];   // 32 KB

    // T1: XCD-aware chunked remap, then triangular decode p -> (bi <= bj)
    int p  = (blockIdx.x % NXCD) * (NPAIR / NXCD) + blockIdx.x / NXCD;
    int bj = (int)((sqrtf(8.0f * (float)p + 1.0f) - 1.0f) * 0.5f);
    while ((bj + 1) * (bj + 2) / 2 <= p) ++bj;
    while (bj * (bj + 1) / 2 > p) --bj;
    int bi = p - bj * (bj + 1) / 2;
    const bool diag = (bi == bj);

    const int tid  = threadIdx.x;
    const int wave = tid >> 6, lane = tid & 63;
    const int wr = wave >> 1, wc = wave & 1;   // 2x2 wave grid, 64x64 each
    const int lrow = lane & 15, quad = lane >> 4;

    f32x4 acc[4][4];
    #pragma unroll
    for (int i = 0; i < 4; ++i)
        #pragma unroll
        for (int j = 0; j < 4; ++j) acc[i][j] = (f32x4){0.f, 0.f, 0.f, 0.f};

    const unsigned short* Bsrc = diag ? As : Bs;   // diag tiles reuse As

    for (int kb = 0; kb < DD; kb += BK) {
        __syncthreads();   // protect LDS from previous iter's readers
        #pragma unroll
        for (int it = 0; it < 8; ++it) {
            int t  = it * 256 + tid;       // chunk-slot 0..2047
            int r  = t >> 4;               // tile row 0..127
            int cc = t & 15;               // LDS chunk slot (16 per row)
            int sc = cc ^ (r & 15);        // global source chunk (swizzle)
            GLOAD_LDS16(zn + (size_t)(bi * TM + r) * DD + kb + sc * 8, As + t * 8);
            if (!diag)
                GLOAD_LDS16(zn + (size_t)(bj * TM + r) * DD + kb + sc * 8, Bs + t * 8);
        }
        __syncthreads();   // drains vmcnt(0) before LDS reads

        #pragma unroll
        for (int s = 0; s < 4; ++s) {      // four K=32 steps per BK=128
            bf16x8 a[4], b[4];
            #pragma unroll
            for (int ti = 0; ti < 4; ++ti) {
                int m = wr * 64 + ti * 16 + lrow;
                int q = (s * 4 + quad) ^ (m & 15);
                a[ti] = *(const bf16x8*)&As[m * BK + q * 8];
            }
            #pragma unroll
            for (int tj = 0; tj < 4; ++tj) {
                int n = wc * 64 + tj * 16 + lrow;
                int q = (s * 4 + quad) ^ (n & 15);
                b[tj] = *(const bf16x8*)&Bsrc[n * BK + q * 8];
            }
            #pragma unroll
            for (int ti = 0; ti < 4; ++ti)
                #pragma unroll
                for (int tj = 0; tj < 4; ++tj)
                    acc[ti][tj] = __builtin_amdgcn_mfma_f32_16x16x32_bf16(
                        a[ti], b[tj], acc[ti][tj], 0, 0, 0);
        }
    }

    // Epilogue. C/D layout (verified, absmax 0.0):
    //   tile row = wr*64 + ti*16 + quad*4 + reg, tile col = wc*64 + tj*16 + lrow
    float rowpart[4][4];   // [ti][reg]
    float colpart[4];      // [tj]
    #pragma unroll
    for (int i = 0; i < 4; ++i) {
        colpart[i] = 0.f;
        #pragma unroll
        for (int r = 0; r < 4; ++r) rowpart[i][r] = 0.f;
    }
    #pragma unroll
    for (int ti = 0; ti < 4; ++ti)
        #pragma unroll
        for (int tj = 0; tj < 4; ++tj)
            #pragma unroll
            for (int reg = 0; reg < 4; ++reg) {
                float e = __expf(acc[ti][tj][reg] * 2.0f);
                rowpart[ti][reg] += e;
                colpart[tj]      += e;
            }

    // row-sums: reduce over lrow (16-lane groups)
    #pragma unroll
    for (int ti = 0; ti < 4; ++ti) {
        #pragma unroll
        for (int reg = 0; reg < 4; ++reg) {
            float v = rowpart[ti][reg];
            v += __shfl_xor(v, 1, 64);
            v += __shfl_xor(v, 2, 64);
            v += __shfl_xor(v, 4, 64);
            v += __shfl_xor(v, 8, 64);
            if (lrow == 0)
                atomicAdd(&rowsum[bi * TM + wr * 64 + ti * 16 + quad * 4 + reg], v);
        }
    }
    // col-sums -> rows of bj tile (transpose); skip on diagonal tiles
    if (!diag) {
        #pragma unroll
        for (int tj = 0; tj < 4; ++tj) {
            float v = colpart[tj];
            v += __shfl_xor(v, 16, 64);
            v += __shfl_xor(v, 32, 64);
            if (quad == 0)
                atomicAdd(&rowsum[bj * TM + wc * 64 + tj * 16 + lrow], v);
        }
    }

    // tile-diagonal extraction: lanes lrow>>2==quad in waves wr==wc hold
    // element (r, r) of the tile at acc[ti][ti][lrow&3], r = wr*64+ti*16+lrow.
    const bool posb = (bj == bi + NTILE / 2);   // bj == bi + 16  (col offset B)
    if ((diag || posb) && wr == wc && (lrow >> 2) == quad) {
        #pragma unroll
        for (int ti = 0; ti < 4; ++ti) {
            float v = 2.0f * acc[ti][ti][lrow & 3];
            int R = bi * TM + wr * 64 + ti * 16 + lrow;
            if (diag) {
                selfsim[R] = v;
            } else {
                possim[R]      = v;   // sim[r][r+B]
                possim[R + BB] = v;   // == sim[r+B][r]
            }
        }
    }
}

// ---------------------------------------------------------------------------
// Kernel C: loss_r = log(rowsum_r - exp(selfsim_r)) - possim_r; block-reduce;
// atomicAdd(out, sum/N). 3 float reads per row — no zn traffic.
// ---------------------------------------------------------------------------
__global__ __launch_bounds__(256) void rowfinal_kernel(
        const float* __restrict__ rowsum, const float* __restrict__ selfsim,
        const float* __restrict__ possim, float* __restrict__ out) {
    __shared__ float s[256];
    int r = blockIdx.x * 256 + threadIdx.x;
    s[threadIdx.x] = logf(rowsum[r] - __expf(selfsim[r])) - possim[r];
    __syncthreads();
    #pragma unroll
    for (int off = 128; off > 0; off >>= 1) {
        if (threadIdx.x < off) s[threadIdx.x] += s[threadIdx.x + off];
        __syncthreads();
    }
    if (threadIdx.x == 0) atomicAdd(out, s[0] * (1.0f / (float)NN));
}

extern "C" void kernel_launch(void* const* d_in, const int* in_sizes, int n_in,
                              void* d_out, int out_size, void* d_ws, size_t ws_size,
                              hipStream_t stream) {
    const float* z_i = (const float*)d_in[0];
    const float* z_j = (const float*)d_in[1];
    float* out = (float*)d_out;

    unsigned short* zn = (unsigned short*)d_ws;                    // N*D bf16 = 4 MB
    float* rowsum  = (float*)((char*)d_ws + (size_t)NN * DD * 2);  // N floats
    float* selfsim = rowsum + NN;                                  // N floats
    float* possim  = selfsim + NN;                                 // N floats

    normalize_kernel<<<NN / 4, 256, 0, stream>>>(z_i, z_j, zn, rowsum, out);
    simexp_kernel<<<NPAIR, 256, 0, stream>>>(zn, rowsum, selfsim, possim);
    rowfinal_kernel<<<NN / 256, 256, 0, stream>>>(rowsum, selfsim, possim, out);
}